// Round 4
// baseline (91.116 us; speedup 1.0000x reference)
//
#include <hip/hip_runtime.h>

#define NCLASS 16
#define D 128
#define EPSF 1e-6f
#define MF 10.0f

// ws layout (floats):
//   [0] sumLoss  [1] sumValid  [2] done-counter (uint)  [3] pad
//   [16 + b*2080 .. ] per-agg-block partial b: S[16*128] | Q[16] | CNT[16]
#define WS_PART 16
#define SLOT 2080            // 2048 + 16 + 16 floats per partial slot

#define AGG_BLOCKS 64
#define AGG_THREADS 512
#define AGG_WAVES 8

// Per-class aggregation -> per-block partials (plain stores; no atomics, no
// memset needed). float4 loads: each wave handles a row PAIR per iteration
// (half-wave per row), 16-class predicated register accumulation.
// Round-2 lesson: never same-address LDS atomics. Round-1 lesson: never
// LDS read-modify-write chains. Registers + shuffle + tree reduce only.
__global__ void __launch_bounds__(AGG_THREADS)
agg_kernel(const float* __restrict__ F, const int* __restrict__ L,
           float* __restrict__ ws, int n) {
    __shared__ __align__(16) float Ssh[AGG_WAVES][NCLASS * D];   // 64 KB
    __shared__ float qsh[AGG_WAVES][NCLASS];
    __shared__ float csh[AGG_WAVES][NCLASS];
    const int tid  = threadIdx.x;
    const int lane = tid & 63;
    const int wv   = tid >> 6;
    const int sub  = lane & 31;       // float4 index within row (32*4 = 128)
    const int half = lane >> 5;       // which row of the pair
    const int gw   = blockIdx.x * AGG_WAVES + wv;           // 0..511
    const int nwv  = AGG_BLOCKS * AGG_WAVES;                // 512 waves
    const int npairs = n >> 1;

    float sx[NCLASS], sy[NCLASS], sz[NCLASS], sw[NCLASS], qa[NCLASS], ca[NCLASS];
    #pragma unroll
    for (int c = 0; c < NCLASS; ++c) { sx[c]=sy[c]=sz[c]=sw[c]=qa[c]=ca[c]=0.f; }

    const float4* __restrict__ F4 = (const float4*)F;
    for (int rp = gw; rp < npairs; rp += nwv) {             // 8 iterations
        const int r = rp * 2 + half;
        const int lc = L[r];                                 // uniform per half
        const float4 v = F4[(size_t)r * 32 + sub];
        const float vv = fmaf(v.x, v.x, fmaf(v.y, v.y, fmaf(v.z, v.z, v.w*v.w)));
        #pragma unroll
        for (int c = 0; c < NCLASS; ++c) {
            const float sel = (lc == c) ? 1.f : 0.f;
            sx[c] = fmaf(sel, v.x, sx[c]);
            sy[c] = fmaf(sel, v.y, sy[c]);
            sz[c] = fmaf(sel, v.z, sz[c]);
            sw[c] = fmaf(sel, v.w, sw[c]);
            qa[c] = fmaf(sel, vv,  qa[c]);
            ca[c] += sel;            // each of 32 lanes counts the row: /32 later
        }
    }
    // combine the two halves for S; full butterfly for scalar Q/CNT
    #pragma unroll
    for (int c = 0; c < NCLASS; ++c) {
        sx[c] += __shfl_xor(sx[c], 32, 64);
        sy[c] += __shfl_xor(sy[c], 32, 64);
        sz[c] += __shfl_xor(sz[c], 32, 64);
        sw[c] += __shfl_xor(sw[c], 32, 64);
        float q = qa[c], cc = ca[c];
        #pragma unroll
        for (int off = 32; off; off >>= 1) {
            q  += __shfl_xor(q, off, 64);
            cc += __shfl_xor(cc, off, 64);
        }
        qa[c] = q; ca[c] = cc;
    }
    if (half == 0) {   // lanes 0..31 own col group sub for every class
        #pragma unroll
        for (int c = 0; c < NCLASS; ++c)
            ((float4*)&Ssh[wv][c * D])[sub] = make_float4(sx[c], sy[c], sz[c], sw[c]);
    }
    if (lane == 0) {
        #pragma unroll
        for (int c = 0; c < NCLASS; ++c) {
            qsh[wv][c] = qa[c];
            csh[wv][c] = ca[c] * (1.f / 32.f);   // undo 32-lane multiplicity
        }
    }
    __syncthreads();
    // block-reduce 8 waves -> per-block partial slot (plain coalesced stores)
    float* __restrict__ base = ws + WS_PART + (size_t)blockIdx.x * SLOT;
    {   // 512 float4 positions, 512 threads: one each
        float4 a = make_float4(0.f, 0.f, 0.f, 0.f);
        #pragma unroll
        for (int w = 0; w < AGG_WAVES; ++w) {
            const float4 t = ((const float4*)Ssh[w])[tid];
            a.x += t.x; a.y += t.y; a.z += t.z; a.w += t.w;
        }
        ((float4*)base)[tid] = a;
    }
    if (tid < NCLASS) {
        float q = 0.f, cc = 0.f;
        #pragma unroll
        for (int w = 0; w < AGG_WAVES; ++w) { q += qsh[w][tid]; cc += csh[w][tid]; }
        base[NCLASS * D + tid] = q;
        base[NCLASS * D + NCLASS + tid] = cc;
    }
    if (blockIdx.x == 0 && tid == 0) {       // init scalars for loss_kernel
        ws[0] = 0.f; ws[1] = 0.f;
        ((unsigned*)ws)[2] = 0u;
    }
}

#define LOSS_BLOCKS 256
#define LOSS_THREADS 256
#define LOSS_WAVES 4

// Prologue: reduce the 64 partial slots into LDS. Main: one wave per row,
// closed-form loss. Epilogue: block reduce -> 2 atomics -> done-counter ->
// last block writes out (final divide fused).
__global__ void __launch_bounds__(LOSS_THREADS)
loss_kernel(const float* __restrict__ F, float* __restrict__ ws,
            const int* __restrict__ L, float* __restrict__ out, int n) {
    __shared__ __align__(16) float S_lds[NCLASS * D];
    __shared__ float Stot[D];
    __shared__ float Q_lds[NCLASS];
    __shared__ float cnt_lds[NCLASS];
    __shared__ float Qtot_s;
    __shared__ float redL[LOSS_WAVES], redV[LOSS_WAVES];

    const int tid = threadIdx.x;
    const float* __restrict__ pb = ws + WS_PART;
    for (int p = tid; p < NCLASS * D / 4; p += LOSS_THREADS) {  // 2 iterations
        float4 a = make_float4(0.f, 0.f, 0.f, 0.f);
        for (int s = 0; s < AGG_BLOCKS; ++s) {
            const float4 t = ((const float4*)(pb + (size_t)s * SLOT))[p];
            a.x += t.x; a.y += t.y; a.z += t.z; a.w += t.w;
        }
        ((float4*)S_lds)[p] = a;
    }
    if (tid < NCLASS) {
        float q = 0.f, cc = 0.f;
        for (int s = 0; s < AGG_BLOCKS; ++s) {
            q  += pb[(size_t)s * SLOT + NCLASS * D + tid];
            cc += pb[(size_t)s * SLOT + NCLASS * D + NCLASS + tid];
        }
        Q_lds[tid] = q; cnt_lds[tid] = cc;
    }
    __syncthreads();
    if (tid < D) {
        float s = 0.f;
        #pragma unroll
        for (int c = 0; c < NCLASS; ++c) s += S_lds[c * D + tid];
        Stot[tid] = s;
    }
    if (tid == 0) {
        float q = 0.f;
        #pragma unroll
        for (int c = 0; c < NCLASS; ++c) q += Q_lds[c];
        Qtot_s = q;
    }
    __syncthreads();

    const int lane = tid & 63;
    const int wv = tid >> 6;
    const int gw = blockIdx.x * LOSS_WAVES + wv;
    const int nw = LOSS_BLOCKS * LOSS_WAVES;     // 1024 waves
    const float nf = (float)n;
    const float2* __restrict__ F2 = (const float2*)F;
    const float2* __restrict__ S2 = (const float2*)S_lds;
    const float2* __restrict__ T2 = (const float2*)Stot;

    float accL = 0.f, accV = 0.f;
    #pragma unroll 2
    for (int r = gw; r < n; r += nw) {           // 8 iterations
        const int c = L[r];                      // wave-uniform
        const float2 v = F2[(size_t)r * 64 + lane];
        const float2 a = S2[c * 64 + lane];
        const float2 t = T2[lane];
        float sq    = fmaf(v.x, v.x, v.y * v.y);
        float dsame = fmaf(v.x, a.x, v.y * a.y);
        float dtot  = fmaf(v.x, t.x, v.y * t.y);
        #pragma unroll
        for (int off = 32; off; off >>= 1) {
            sq    += __shfl_xor(sq, off, 64);
            dsame += __shfl_xor(dsame, off, 64);
            dtot  += __shfl_xor(dtot, off, 64);
        }
        const float cntc   = cnt_lds[c];
        const float counts = cntc - 1.f;
        const float same_sum = counts * sq + sq + Q_lds[c] - 2.f * dsame;
        const float diff_sum = (nf - cntc) * sq + (Qtot_s - Q_lds[c])
                               - 2.f * (dtot - dsame);
        const float loss = same_sum / (counts + EPSF)
                         - diff_sum / (nf - cntc + EPSF) + MF;
        const float valid = counts > 0.5f ? 1.f : 0.f;
        accL += (loss > 0.f ? loss : 0.f) * valid;
        accV += valid;
    }
    if (lane == 0) { redL[wv] = accL; redV[wv] = accV; }
    __syncthreads();
    if (tid == 0) {
        float sL = 0.f, sV = 0.f;
        #pragma unroll
        for (int w = 0; w < LOSS_WAVES; ++w) { sL += redL[w]; sV += redV[w]; }
        atomicAdd(&ws[0], sL);
        atomicAdd(&ws[1], sV);
        __threadfence();
        unsigned done = __hip_atomic_fetch_add((unsigned*)ws + 2, 1u,
                                               __ATOMIC_ACQ_REL,
                                               __HIP_MEMORY_SCOPE_AGENT);
        if (done == (unsigned)(LOSS_BLOCKS - 1)) {   // last block: final divide
            float sl = __hip_atomic_load(&ws[0], __ATOMIC_RELAXED,
                                         __HIP_MEMORY_SCOPE_AGENT);
            float sv = __hip_atomic_load(&ws[1], __ATOMIC_RELAXED,
                                         __HIP_MEMORY_SCOPE_AGENT);
            out[0] = sl / fmaxf(sv, 1.f);
        }
    }
}

extern "C" void kernel_launch(void* const* d_in, const int* in_sizes, int n_in,
                              void* d_out, int out_size, void* d_ws, size_t ws_size,
                              hipStream_t stream) {
    const float* F = (const float*)d_in[0];
    const int* L = (const int*)d_in[1];
    float* out = (float*)d_out;
    float* ws = (float*)d_ws;
    const int n = in_sizes[1];  // 8192 rows; D = in_sizes[0]/n = 128

    agg_kernel<<<AGG_BLOCKS, AGG_THREADS, 0, stream>>>(F, L, ws, n);
    loss_kernel<<<LOSS_BLOCKS, LOSS_THREADS, 0, stream>>>(F, ws, L, out, n);
}